// Round 1
// baseline (362.490 us; speedup 1.0000x reference)
//
#include <hip/hip_runtime.h>
#include <hip/hip_bf16.h>

#define M_ROWS 16384
#define N_IN   512
#define N_HID  1024
#define K_TOT  1536   // 512 + 1024
#define N_TOT  4096   // 4 gates * 1024

typedef __attribute__((ext_vector_type(4))) float f32x4;
typedef __attribute__((ext_vector_type(8))) short bf16x8;

__device__ __forceinline__ ushort f2bf(float f) {
    union { float f; unsigned u; } un; un.f = f;
    unsigned u = un.u;
    u += 0x7fffu + ((u >> 16) & 1u);   // RNE
    return (ushort)(u >> 16);
}

// ---------------- prep kernels ----------------

// A_cat[m][k] bf16, k<512 from x, else from h
__global__ void build_A(const float* __restrict__ x, const float* __restrict__ h,
                        ushort* __restrict__ A) {
    const int total = M_ROWS * K_TOT / 4;
    for (int p = blockIdx.x * blockDim.x + threadIdx.x; p < total;
         p += gridDim.x * blockDim.x) {
        int flat = p * 4;
        int row = flat / K_TOT;
        int col = flat - row * K_TOT;
        const float* src = (col < N_IN)
            ? (x + (size_t)row * N_IN + col)
            : (h + (size_t)row * N_HID + (col - N_IN));
        float4 v = *(const float4*)src;
        ushort4 o;
        o.x = f2bf(v.x); o.y = f2bf(v.y); o.z = f2bf(v.z); o.w = f2bf(v.w);
        *(ushort4*)(A + flat) = o;
    }
}

// W_perm row p encodes (block bn, wave col-half cc, gate g, unit u):
//   bn = p>>7, tt = p&127, cc = tt>>6, ss = tt&63, g = ss>>4, u = ss&15
//   source row j = bn*32 + cc*16 + u of gate g;  k<512 -> Wx_g, else Wh_g
__global__ void build_W(const float* __restrict__ Wii, const float* __restrict__ Wif,
                        const float* __restrict__ Wig, const float* __restrict__ Wio,
                        const float* __restrict__ Whi, const float* __restrict__ Whf,
                        const float* __restrict__ Whg, const float* __restrict__ Who,
                        ushort* __restrict__ Wp) {
    const int total = N_TOT * K_TOT / 4;
    for (int p = blockIdx.x * blockDim.x + threadIdx.x; p < total;
         p += gridDim.x * blockDim.x) {
        int flat = p * 4;
        int prow = flat / K_TOT;
        int col = flat - prow * K_TOT;
        int bn = prow >> 7;
        int tt = prow & 127;
        int cc = (tt >> 6) & 1;
        int ss = tt & 63;
        int g  = ss >> 4;
        int u  = ss & 15;
        int j  = bn * 32 + cc * 16 + u;
        const float* src;
        if (col < N_IN) {
            const float* Wx = (g == 0) ? Wii : (g == 1) ? Wif : (g == 2) ? Wig : Wio;
            src = Wx + (size_t)j * N_IN + col;
        } else {
            const float* Wh = (g == 0) ? Whi : (g == 1) ? Whf : (g == 2) ? Whg : Who;
            src = Wh + (size_t)j * N_HID + (col - N_IN);
        }
        float4 v = *(const float4*)src;
        ushort4 o;
        o.x = f2bf(v.x); o.y = f2bf(v.y); o.z = f2bf(v.z); o.w = f2bf(v.w);
        *(ushort4*)(Wp + flat) = o;
    }
}

// bias[n] = bx_g[j] + bh_g[j], natural order n = g*1024 + j
__global__ void build_bias(const float* __restrict__ bii, const float* __restrict__ bif,
                           const float* __restrict__ big, const float* __restrict__ bio,
                           const float* __restrict__ bhi, const float* __restrict__ bhf,
                           const float* __restrict__ bhg, const float* __restrict__ bho,
                           float* __restrict__ bias) {
    int n = blockIdx.x * blockDim.x + threadIdx.x;
    if (n >= N_TOT) return;
    int g = n >> 10, j = n & 1023;
    const float* bx = (g == 0) ? bii : (g == 1) ? bif : (g == 2) ? big : bio;
    const float* bh = (g == 0) ? bhi : (g == 1) ? bhf : (g == 2) ? bhg : bho;
    bias[n] = bx[j] + bh[j];
}

// ---------------- fused GEMM + LSTM epilogue ----------------
// 128x128 tile, BK=64, 4 waves (2x2), each wave 64x64 (4x4 frags of 16x16x32).
// Wave col-half covers 4 gates x 16 units -> all 4 gates of a unit live in
// acc[mi][0..3] of the same lane -> fully in-register epilogue.

__device__ __forceinline__ float sigmoid_f(float z) {
    return 1.f / (1.f + __expf(-z));
}
__device__ __forceinline__ float tanh_f(float z) {
    z = fminf(fmaxf(z, -15.f), 15.f);
    float e = __expf(2.f * z);
    return (e - 1.f) / (e + 1.f);
}

__global__ __launch_bounds__(256) void lstm_gemm(
        const ushort* __restrict__ A, const ushort* __restrict__ W,
        const float* __restrict__ bias, const float* __restrict__ cin,
        float* __restrict__ outc, float* __restrict__ outh) {
    __shared__ ushort As[128 * 64];
    __shared__ ushort Bs[128 * 64];

    const int t    = threadIdx.x;
    const int wid  = t >> 6;
    const int lane = t & 63;
    const int bm = blockIdx.x;
    const int bn = blockIdx.y;
    const int m0 = bm * 128;
    const int wr = wid >> 1, wc = wid & 1;

    f32x4 acc[4][4] = {};

    const int frow = t >> 3;   // 0..31, staging row (load i adds i*32)
    const int fch  = t & 7;    // 16B chunk within a 64-elem row
    const ushort* gA = A + (size_t)(m0 + frow) * K_TOT + fch * 8;
    const ushort* gB = W + (size_t)(bn * 128 + frow) * K_TOT + fch * 8;

    for (int k0 = 0; k0 < K_TOT; k0 += 64) {
#pragma unroll
        for (int i = 0; i < 4; ++i) {
            __builtin_amdgcn_global_load_lds(
                (const __attribute__((address_space(1))) void*)(gA + (size_t)i * 32 * K_TOT + k0),
                (__attribute__((address_space(3))) void*)(As + (i * 256 + wid * 64) * 8),
                16, 0, 0);
            __builtin_amdgcn_global_load_lds(
                (const __attribute__((address_space(1))) void*)(gB + (size_t)i * 32 * K_TOT + k0),
                (__attribute__((address_space(3))) void*)(Bs + (i * 256 + wid * 64) * 8),
                16, 0, 0);
        }
        __syncthreads();
#pragma unroll
        for (int kk = 0; kk < 2; ++kk) {
            const int lrow = lane & 15;
            const int lk   = kk * 32 + (lane >> 4) * 8;
            bf16x8 af[4], bfr[4];
#pragma unroll
            for (int mi = 0; mi < 4; ++mi)
                af[mi] = *(const bf16x8*)&As[(wr * 64 + mi * 16 + lrow) * 64 + lk];
#pragma unroll
            for (int ni = 0; ni < 4; ++ni)
                bfr[ni] = *(const bf16x8*)&Bs[(wc * 64 + ni * 16 + lrow) * 64 + lk];
#pragma unroll
            for (int mi = 0; mi < 4; ++mi)
#pragma unroll
                for (int ni = 0; ni < 4; ++ni)
                    acc[mi][ni] = __builtin_amdgcn_mfma_f32_16x16x32_bf16(
                        af[mi], bfr[ni], acc[mi][ni], 0, 0, 0);
        }
        __syncthreads();
    }

    // epilogue: lane owns unit (bn*32 + wc*16 + (lane&15)), gates = acc[mi][0..3]
    const int unit = bn * 32 + wc * 16 + (lane & 15);
    const float b0 = bias[unit];
    const float b1 = bias[1024 + unit];
    const float b2 = bias[2048 + unit];
    const float b3 = bias[3072 + unit];
    const int r0 = m0 + wr * 64 + (lane >> 4) * 4;
#pragma unroll
    for (int mi = 0; mi < 4; ++mi) {
#pragma unroll
        for (int q = 0; q < 4; ++q) {
            const int row = r0 + mi * 16 + q;
            const size_t off = (size_t)row * N_HID + unit;
            float zi = acc[mi][0][q] + b0;
            float zf = acc[mi][1][q] + b1;
            float zg = acc[mi][2][q] + b2;
            float zo = acc[mi][3][q] + b3;
            float it = sigmoid_f(zi);
            float ft = sigmoid_f(zf);
            float gt = tanh_f(zg);
            float ot = sigmoid_f(zo);
            float ct = ft * cin[off] + it * gt;
            float ht = ot * tanh_f(ct);
            outc[off] = ct;
            outh[off] = ht;
        }
    }
}

// ---------------- launch ----------------

extern "C" void kernel_launch(void* const* d_in, const int* in_sizes, int n_in,
                              void* d_out, int out_size, void* d_ws, size_t ws_size,
                              hipStream_t stream) {
    const float* x = (const float*)d_in[0];
    const float* c = (const float*)d_in[1];
    const float* h = (const float*)d_in[2];
    const float* Wii = (const float*)d_in[3];  const float* bii = (const float*)d_in[4];
    const float* Wif = (const float*)d_in[5];  const float* bif = (const float*)d_in[6];
    const float* Wig = (const float*)d_in[7];  const float* big = (const float*)d_in[8];
    const float* Wio = (const float*)d_in[9];  const float* bio = (const float*)d_in[10];
    const float* Whi = (const float*)d_in[11]; const float* bhi = (const float*)d_in[12];
    const float* Whf = (const float*)d_in[13]; const float* bhf = (const float*)d_in[14];
    const float* Whg = (const float*)d_in[15]; const float* bhg = (const float*)d_in[16];
    const float* Who = (const float*)d_in[17]; const float* bho = (const float*)d_in[18];

    // workspace layout (bytes)
    char* ws = (char*)d_ws;
    ushort* A_cat  = (ushort*)ws;                                   // 16384*1536*2 = 50,331,648
    ushort* W_perm = (ushort*)(ws + (size_t)M_ROWS * K_TOT * 2);    // 4096*1536*2 = 12,582,912
    float*  biasc  = (float*)(ws + (size_t)M_ROWS * K_TOT * 2
                                 + (size_t)N_TOT * K_TOT * 2);      // 4096*4

    float* outc = (float*)d_out;
    float* outh = (float*)d_out + (size_t)M_ROWS * N_HID;

    hipLaunchKernelGGL(build_A, dim3(2048), dim3(256), 0, stream, x, h, A_cat);
    hipLaunchKernelGGL(build_W, dim3(1024), dim3(256), 0, stream,
                       Wii, Wif, Wig, Wio, Whi, Whf, Whg, Who, W_perm);
    hipLaunchKernelGGL(build_bias, dim3(16), dim3(256), 0, stream,
                       bii, bif, big, bio, bhi, bhf, bhg, bho, biasc);
    hipLaunchKernelGGL(lstm_gemm, dim3(M_ROWS / 128, N_TOT / 128), dim3(256), 0, stream,
                       A_cat, W_perm, biasc, c, outc, outh);
}

// Round 2
// 298.020 us; speedup vs baseline: 1.2163x; 1.2163x over previous
//
#include <hip/hip_runtime.h>
#include <hip/hip_bf16.h>

#define M_ROWS 16384
#define N_IN   512
#define N_HID  1024
#define K_TOT  1536   // 512 + 1024
#define N_TOT  4096   // 4 gates * 1024

typedef __attribute__((ext_vector_type(4))) float f32x4;
typedef __attribute__((ext_vector_type(8))) short bf16x8;

__device__ __forceinline__ ushort f2bf(float f) {
    union { float f; unsigned u; } un; un.f = f;
    unsigned u = un.u;
    u += 0x7fffu + ((u >> 16) & 1u);   // RNE
    return (ushort)(u >> 16);
}

// ---------------- prep kernels ----------------

// A_cat[m][k] bf16, k<512 from x, else from h
__global__ void build_A(const float* __restrict__ x, const float* __restrict__ h,
                        ushort* __restrict__ A) {
    const int total = M_ROWS * K_TOT / 4;
    for (int p = blockIdx.x * blockDim.x + threadIdx.x; p < total;
         p += gridDim.x * blockDim.x) {
        int flat = p * 4;
        int row = flat / K_TOT;
        int col = flat - row * K_TOT;
        const float* src = (col < N_IN)
            ? (x + (size_t)row * N_IN + col)
            : (h + (size_t)row * N_HID + (col - N_IN));
        float4 v = *(const float4*)src;
        ushort4 o;
        o.x = f2bf(v.x); o.y = f2bf(v.y); o.z = f2bf(v.z); o.w = f2bf(v.w);
        *(ushort4*)(A + flat) = o;
    }
}

// W_perm row p encodes (block bn, wave col-half cc, gate g, unit u):
//   bn = p>>7, tt = p&127, cc = tt>>6, ss = tt&63, g = ss>>4, u = ss&15
//   source row j = bn*32 + cc*16 + u of gate g;  k<512 -> Wx_g, else Wh_g
__global__ void build_W(const float* __restrict__ Wii, const float* __restrict__ Wif,
                        const float* __restrict__ Wig, const float* __restrict__ Wio,
                        const float* __restrict__ Whi, const float* __restrict__ Whf,
                        const float* __restrict__ Whg, const float* __restrict__ Who,
                        ushort* __restrict__ Wp) {
    const int total = N_TOT * K_TOT / 4;
    for (int p = blockIdx.x * blockDim.x + threadIdx.x; p < total;
         p += gridDim.x * blockDim.x) {
        int flat = p * 4;
        int prow = flat / K_TOT;
        int col = flat - prow * K_TOT;
        int bn = prow >> 7;
        int tt = prow & 127;
        int cc = (tt >> 6) & 1;
        int ss = tt & 63;
        int g  = ss >> 4;
        int u  = ss & 15;
        int j  = bn * 32 + cc * 16 + u;
        const float* src;
        if (col < N_IN) {
            const float* Wx = (g == 0) ? Wii : (g == 1) ? Wif : (g == 2) ? Wig : Wio;
            src = Wx + (size_t)j * N_IN + col;
        } else {
            const float* Wh = (g == 0) ? Whi : (g == 1) ? Whf : (g == 2) ? Whg : Who;
            src = Wh + (size_t)j * N_HID + (col - N_IN);
        }
        float4 v = *(const float4*)src;
        ushort4 o;
        o.x = f2bf(v.x); o.y = f2bf(v.y); o.z = f2bf(v.z); o.w = f2bf(v.w);
        *(ushort4*)(Wp + flat) = o;
    }
}

// bias[n] = bx_g[j] + bh_g[j], natural order n = g*1024 + j
__global__ void build_bias(const float* __restrict__ bii, const float* __restrict__ bif,
                           const float* __restrict__ big, const float* __restrict__ bio,
                           const float* __restrict__ bhi, const float* __restrict__ bhf,
                           const float* __restrict__ bhg, const float* __restrict__ bho,
                           float* __restrict__ bias) {
    int n = blockIdx.x * blockDim.x + threadIdx.x;
    if (n >= N_TOT) return;
    int g = n >> 10, j = n & 1023;
    const float* bx = (g == 0) ? bii : (g == 1) ? bif : (g == 2) ? big : bio;
    const float* bh = (g == 0) ? bhi : (g == 1) ? bhf : (g == 2) ? bhg : bho;
    bias[n] = bx[j] + bh[j];
}

// ---------------- fused GEMM + LSTM epilogue ----------------
// 128x128 tile, BK=64, 4 waves (2x2), each wave 64x64 (4x4 frags of 16x16x32).
// LDS tiles are chunk-XOR-swizzled: LDS slot (row, c') holds global chunk
// c = c' ^ (row&7). global_load_lds writes linearly, so the swizzle is
// applied on the GLOBAL source address (per-lane) and on the ds_read address
// (rule #21: both-sides-or-neither).

__device__ __forceinline__ float sigmoid_f(float z) {
    return 1.f / (1.f + __expf(-z));
}
__device__ __forceinline__ float tanh_f(float z) {
    z = fminf(fmaxf(z, -15.f), 15.f);
    float e = __expf(2.f * z);
    return (e - 1.f) / (e + 1.f);
}

__global__ __launch_bounds__(256) void lstm_gemm(
        const ushort* __restrict__ A, const ushort* __restrict__ W,
        const float* __restrict__ bias, const float* __restrict__ cin,
        float* __restrict__ outc, float* __restrict__ outh) {
    __shared__ ushort As[128 * 64];
    __shared__ ushort Bs[128 * 64];

    const int t    = threadIdx.x;
    const int wid  = t >> 6;
    const int lane = t & 63;
    const int bm = blockIdx.x;
    const int bn = blockIdx.y;
    const int m0 = bm * 128;
    const int wr = wid >> 1, wc = wid & 1;

    f32x4 acc[4][4] = {};

    const int frow = t >> 3;                       // 0..31, staging row (load i adds i*32)
    const int fch  = (t & 7) ^ ((t >> 3) & 7);     // swizzled source chunk (involution)
    const ushort* gA = A + (size_t)(m0 + frow) * K_TOT + fch * 8;
    const ushort* gB = W + (size_t)(bn * 128 + frow) * K_TOT + fch * 8;

    for (int k0 = 0; k0 < K_TOT; k0 += 64) {
#pragma unroll
        for (int i = 0; i < 4; ++i) {
            __builtin_amdgcn_global_load_lds(
                (const __attribute__((address_space(1))) void*)(gA + (size_t)i * 32 * K_TOT + k0),
                (__attribute__((address_space(3))) void*)(As + (i * 256 + wid * 64) * 8),
                16, 0, 0);
            __builtin_amdgcn_global_load_lds(
                (const __attribute__((address_space(1))) void*)(gB + (size_t)i * 32 * K_TOT + k0),
                (__attribute__((address_space(3))) void*)(Bs + (i * 256 + wid * 64) * 8),
                16, 0, 0);
        }
        __syncthreads();
        {
            const int lrow  = lane & 15;
            const int cswz  = lane & 7;       // row&7 for every fragment row
            const int cbase = lane >> 4;      // which 16B chunk of the 32-elem k-slice
#pragma unroll
            for (int kk = 0; kk < 2; ++kk) {
                const int lkk = ((kk * 4 + cbase) ^ cswz) * 8;  // swizzled read chunk
                bf16x8 af[4], bfr[4];
#pragma unroll
                for (int mi = 0; mi < 4; ++mi)
                    af[mi] = *(const bf16x8*)&As[(wr * 64 + mi * 16 + lrow) * 64 + lkk];
#pragma unroll
                for (int ni = 0; ni < 4; ++ni)
                    bfr[ni] = *(const bf16x8*)&Bs[(wc * 64 + ni * 16 + lrow) * 64 + lkk];
#pragma unroll
                for (int mi = 0; mi < 4; ++mi)
#pragma unroll
                    for (int ni = 0; ni < 4; ++ni)
                        acc[mi][ni] = __builtin_amdgcn_mfma_f32_16x16x32_bf16(
                            af[mi], bfr[ni], acc[mi][ni], 0, 0, 0);
            }
        }
        __syncthreads();
    }

    // epilogue: lane owns unit (bn*32 + wc*16 + (lane&15)), gates = acc[mi][0..3]
    const int unit = bn * 32 + wc * 16 + (lane & 15);
    const float b0 = bias[unit];
    const float b1 = bias[1024 + unit];
    const float b2 = bias[2048 + unit];
    const float b3 = bias[3072 + unit];
    const int r0 = m0 + wr * 64 + (lane >> 4) * 4;
#pragma unroll
    for (int mi = 0; mi < 4; ++mi) {
#pragma unroll
        for (int q = 0; q < 4; ++q) {
            const int row = r0 + mi * 16 + q;
            const size_t off = (size_t)row * N_HID + unit;
            float zi = acc[mi][0][q] + b0;
            float zf = acc[mi][1][q] + b1;
            float zg = acc[mi][2][q] + b2;
            float zo = acc[mi][3][q] + b3;
            float it = sigmoid_f(zi);
            float ft = sigmoid_f(zf);
            float gt = tanh_f(zg);
            float ot = sigmoid_f(zo);
            float ct = ft * cin[off] + it * gt;
            float ht = ot * tanh_f(ct);
            outc[off] = ct;
            outh[off] = ht;
        }
    }
}

// ---------------- launch ----------------

extern "C" void kernel_launch(void* const* d_in, const int* in_sizes, int n_in,
                              void* d_out, int out_size, void* d_ws, size_t ws_size,
                              hipStream_t stream) {
    const float* x = (const float*)d_in[0];
    const float* c = (const float*)d_in[1];
    const float* h = (const float*)d_in[2];
    const float* Wii = (const float*)d_in[3];  const float* bii = (const float*)d_in[4];
    const float* Wif = (const float*)d_in[5];  const float* bif = (const float*)d_in[6];
    const float* Wig = (const float*)d_in[7];  const float* big = (const float*)d_in[8];
    const float* Wio = (const float*)d_in[9];  const float* bio = (const float*)d_in[10];
    const float* Whi = (const float*)d_in[11]; const float* bhi = (const float*)d_in[12];
    const float* Whf = (const float*)d_in[13]; const float* bhf = (const float*)d_in[14];
    const float* Whg = (const float*)d_in[15]; const float* bhg = (const float*)d_in[16];
    const float* Who = (const float*)d_in[17]; const float* bho = (const float*)d_in[18];

    // workspace layout (bytes)
    char* ws = (char*)d_ws;
    ushort* A_cat  = (ushort*)ws;                                   // 16384*1536*2 = 50,331,648
    ushort* W_perm = (ushort*)(ws + (size_t)M_ROWS * K_TOT * 2);    // 4096*1536*2 = 12,582,912
    float*  biasc  = (float*)(ws + (size_t)M_ROWS * K_TOT * 2
                                 + (size_t)N_TOT * K_TOT * 2);      // 4096*4

    float* outc = (float*)d_out;
    float* outh = (float*)d_out + (size_t)M_ROWS * N_HID;

    hipLaunchKernelGGL(build_A, dim3(2048), dim3(256), 0, stream, x, h, A_cat);
    hipLaunchKernelGGL(build_W, dim3(1024), dim3(256), 0, stream,
                       Wii, Wif, Wig, Wio, Whi, Whf, Whg, Who, W_perm);
    hipLaunchKernelGGL(build_bias, dim3(16), dim3(256), 0, stream,
                       bii, bif, big, bio, bhi, bhf, bhg, bho, biasc);
    hipLaunchKernelGGL(lstm_gemm, dim3(M_ROWS / 128, N_TOT / 128), dim3(256), 0, stream,
                       A_cat, W_perm, biasc, c, outc, outh);
}

// Round 3
// 297.601 us; speedup vs baseline: 1.2180x; 1.0014x over previous
//
#include <hip/hip_runtime.h>
#include <hip/hip_bf16.h>

#define M_ROWS 16384
#define N_IN   512
#define N_HID  1024
#define K_TOT  1536   // 512 + 1024
#define N_TOT  4096   // 4 gates * 1024

#define BM 256
#define BN 128
#define BK 32
#define KTILES 48     // K_TOT / BK

typedef __attribute__((ext_vector_type(4))) float f32x4;
typedef __attribute__((ext_vector_type(8))) short bf16x8;

__device__ __forceinline__ ushort f2bf(float f) {
    union { float f; unsigned u; } un; un.f = f;
    unsigned u = un.u;
    u += 0x7fffu + ((u >> 16) & 1u);   // RNE
    return (ushort)(u >> 16);
}

// ---------------- prep kernels ----------------

__global__ void build_A(const float* __restrict__ x, const float* __restrict__ h,
                        ushort* __restrict__ A) {
    const int total = M_ROWS * K_TOT / 4;
    for (int p = blockIdx.x * blockDim.x + threadIdx.x; p < total;
         p += gridDim.x * blockDim.x) {
        int flat = p * 4;
        int row = flat / K_TOT;
        int col = flat - row * K_TOT;
        const float* src = (col < N_IN)
            ? (x + (size_t)row * N_IN + col)
            : (h + (size_t)row * N_HID + (col - N_IN));
        float4 v = *(const float4*)src;
        ushort4 o;
        o.x = f2bf(v.x); o.y = f2bf(v.y); o.z = f2bf(v.z); o.w = f2bf(v.w);
        *(ushort4*)(A + flat) = o;
    }
}

// W_perm row p: bn = p>>7 (128 rows/block), cc = (p>>6)&1, g = (p>>4)&3, u = p&15
// source row j = bn*32 + cc*16 + u of gate g; k<512 -> Wx_g else Wh_g
__global__ void build_W(const float* __restrict__ Wii, const float* __restrict__ Wif,
                        const float* __restrict__ Wig, const float* __restrict__ Wio,
                        const float* __restrict__ Whi, const float* __restrict__ Whf,
                        const float* __restrict__ Whg, const float* __restrict__ Who,
                        ushort* __restrict__ Wp) {
    const int total = N_TOT * K_TOT / 4;
    for (int p = blockIdx.x * blockDim.x + threadIdx.x; p < total;
         p += gridDim.x * blockDim.x) {
        int flat = p * 4;
        int prow = flat / K_TOT;
        int col = flat - prow * K_TOT;
        int bn = prow >> 7;
        int tt = prow & 127;
        int cc = (tt >> 6) & 1;
        int ss = tt & 63;
        int g  = ss >> 4;
        int u  = ss & 15;
        int j  = bn * 32 + cc * 16 + u;
        const float* src;
        if (col < N_IN) {
            const float* Wx = (g == 0) ? Wii : (g == 1) ? Wif : (g == 2) ? Wig : Wio;
            src = Wx + (size_t)j * N_IN + col;
        } else {
            const float* Wh = (g == 0) ? Whi : (g == 1) ? Whf : (g == 2) ? Whg : Who;
            src = Wh + (size_t)j * N_HID + (col - N_IN);
        }
        float4 v = *(const float4*)src;
        ushort4 o;
        o.x = f2bf(v.x); o.y = f2bf(v.y); o.z = f2bf(v.z); o.w = f2bf(v.w);
        *(ushort4*)(Wp + flat) = o;
    }
}

__global__ void build_bias(const float* __restrict__ bii, const float* __restrict__ bif,
                           const float* __restrict__ big, const float* __restrict__ bio,
                           const float* __restrict__ bhi, const float* __restrict__ bhf,
                           const float* __restrict__ bhg, const float* __restrict__ bho,
                           float* __restrict__ bias) {
    int n = blockIdx.x * blockDim.x + threadIdx.x;
    if (n >= N_TOT) return;
    int g = n >> 10, j = n & 1023;
    const float* bx = (g == 0) ? bii : (g == 1) ? bif : (g == 2) ? big : bio;
    const float* bh = (g == 0) ? bhi : (g == 1) ? bhf : (g == 2) ? bhg : bho;
    bias[n] = bx[j] + bh[j];
}

// ---------------- fused GEMM + LSTM epilogue ----------------
// 256x128 tile, BK=32, 4 waves (2M x 2N), per-wave 128x64 (8mi x 4ni frags).
// 3 LDS buffers, 2-tile-deep prefetch, counted s_waitcnt vmcnt(6), raw
// s_barrier (no compiler vmcnt(0) drain), sched_barrier(0) fences.
// Ledger: tile t in buf t%3. Iter t issues STAGE(t+2) -> buf[(t+2)%3], which
// held tile t-1 (fully read before previous barrier). vmcnt(6) at iter end
// retires tile t+1's 6 loads (issued one full iteration earlier).

__device__ __forceinline__ float sigmoid_f(float z) {
    return 1.f / (1.f + __expf(-z));
}
__device__ __forceinline__ float tanh_f(float z) {
    z = fminf(fmaxf(z, -15.f), 15.f);
    float e = __expf(2.f * z);
    return (e - 1.f) / (e + 1.f);
}

__global__ __launch_bounds__(256, 2) void lstm_gemm(
        const ushort* __restrict__ A, const ushort* __restrict__ W,
        const float* __restrict__ bias, const float* __restrict__ cin,
        float* __restrict__ outc, float* __restrict__ outh) {
    __shared__ ushort sA[3][BM * BK];   // 3 x 16 KB
    __shared__ ushort sW[3][BN * BK];   // 3 x  8 KB   (72 KB total)

    const int tid  = threadIdx.x;
    const int wid  = tid >> 6;
    const int lane = tid & 63;
    const int wr = wid >> 1, wc = wid & 1;
    const int m0 = blockIdx.x * BM;
    const int n0 = blockIdx.y * BN;

    f32x4 acc[8][4] = {};

    // staging map: call i covers rows i*64 + (tid>>2), 16B chunk tid&3
    const int srow = tid >> 2;
    const int schk = tid & 3;
    const ushort* gA = A + (size_t)(m0 + srow) * K_TOT + schk * 8;
    const ushort* gW = W + (size_t)(n0 + srow) * K_TOT + schk * 8;

#define STAGE(bufi, ks) do {                                                     \
    _Pragma("unroll")                                                            \
    for (int i = 0; i < 4; ++i)                                                  \
        __builtin_amdgcn_global_load_lds(                                        \
            (const __attribute__((address_space(1))) void*)(gA + (size_t)i * 64 * K_TOT + (ks)), \
            (__attribute__((address_space(3))) void*)(&sA[bufi][i * 2048 + tid * 8]), \
            16, 0, 0);                                                           \
    _Pragma("unroll")                                                            \
    for (int i = 0; i < 2; ++i)                                                  \
        __builtin_amdgcn_global_load_lds(                                        \
            (const __attribute__((address_space(1))) void*)(gW + (size_t)i * 64 * K_TOT + (ks)), \
            (__attribute__((address_space(3))) void*)(&sW[bufi][i * 2048 + tid * 8]), \
            16, 0, 0);                                                           \
} while (0)

#define COMPUTE(bufi) do {                                                       \
    const int lrow = lane & 15;                                                  \
    const int ksl  = (lane >> 4) * 8;                                            \
    bf16x8 wf[4];                                                                \
    _Pragma("unroll")                                                            \
    for (int ni = 0; ni < 4; ++ni)                                               \
        wf[ni] = *(const bf16x8*)&sW[bufi][(wc * 64 + ni * 16 + lrow) * BK + ksl]; \
    __builtin_amdgcn_s_setprio(1);                                               \
    _Pragma("unroll")                                                            \
    for (int mi = 0; mi < 8; ++mi) {                                             \
        bf16x8 afm = *(const bf16x8*)&sA[bufi][(wr * 128 + mi * 16 + lrow) * BK + ksl]; \
        _Pragma("unroll")                                                        \
        for (int ni = 0; ni < 4; ++ni)                                           \
            acc[mi][ni] = __builtin_amdgcn_mfma_f32_16x16x32_bf16(               \
                afm, wf[ni], acc[mi][ni], 0, 0, 0);                              \
    }                                                                            \
    __builtin_amdgcn_s_setprio(0);                                               \
} while (0)

#define KSTEP_SYNC() do {                                                        \
    __builtin_amdgcn_sched_barrier(0);                                           \
    asm volatile("s_waitcnt vmcnt(6)" ::: "memory");                             \
    __builtin_amdgcn_s_barrier();                                                \
    __builtin_amdgcn_sched_barrier(0);                                           \
} while (0)

    // prologue: stage tiles 0,1; wait tile 0 landed
    STAGE(0, 0);
    STAGE(1, BK);
    __builtin_amdgcn_sched_barrier(0);
    asm volatile("s_waitcnt vmcnt(6)" ::: "memory");
    __builtin_amdgcn_s_barrier();
    __builtin_amdgcn_sched_barrier(0);

    for (int tt = 0; tt < 16; ++tt) {
#pragma unroll
        for (int u = 0; u < 3; ++u) {
            const int t3 = tt * 3 + u;
            const int ks = ((t3 + 2 <= KTILES - 1) ? (t3 + 2) : (KTILES - 1)) * BK;
            STAGE((u + 2) % 3, ks);
            COMPUTE(u);
            KSTEP_SYNC();
        }
    }

    // epilogue: lane owns unit (blockIdx.y*32 + wc*16 + (lane&15)), gates = acc[mi][0..3]
    const int unit = blockIdx.y * 32 + wc * 16 + (lane & 15);
    const float b0 = bias[unit];
    const float b1 = bias[1024 + unit];
    const float b2 = bias[2048 + unit];
    const float b3 = bias[3072 + unit];
    const int r0 = m0 + wr * 128 + (lane >> 4) * 4;
#pragma unroll
    for (int mi = 0; mi < 8; ++mi) {
#pragma unroll
        for (int q = 0; q < 4; ++q) {
            const int row = r0 + mi * 16 + q;
            const size_t off = (size_t)row * N_HID + unit;
            float zi = acc[mi][0][q] + b0;
            float zf = acc[mi][1][q] + b1;
            float zg = acc[mi][2][q] + b2;
            float zo = acc[mi][3][q] + b3;
            float it = sigmoid_f(zi);
            float ft = sigmoid_f(zf);
            float gt = tanh_f(zg);
            float ot = sigmoid_f(zo);
            float ct = ft * cin[off] + it * gt;
            float ht = ot * tanh_f(ct);
            outc[off] = ct;
            outh[off] = ht;
        }
    }
#undef STAGE
#undef COMPUTE
#undef KSTEP_SYNC
}

// ---------------- launch ----------------

extern "C" void kernel_launch(void* const* d_in, const int* in_sizes, int n_in,
                              void* d_out, int out_size, void* d_ws, size_t ws_size,
                              hipStream_t stream) {
    const float* x = (const float*)d_in[0];
    const float* c = (const float*)d_in[1];
    const float* h = (const float*)d_in[2];
    const float* Wii = (const float*)d_in[3];  const float* bii = (const float*)d_in[4];
    const float* Wif = (const float*)d_in[5];  const float* bif = (const float*)d_in[6];
    const float* Wig = (const float*)d_in[7];  const float* big = (const float*)d_in[8];
    const float* Wio = (const float*)d_in[9];  const float* bio = (const float*)d_in[10];
    const float* Whi = (const float*)d_in[11]; const float* bhi = (const float*)d_in[12];
    const float* Whf = (const float*)d_in[13]; const float* bhf = (const float*)d_in[14];
    const float* Whg = (const float*)d_in[15]; const float* bhg = (const float*)d_in[16];
    const float* Who = (const float*)d_in[17]; const float* bho = (const float*)d_in[18];

    char* ws = (char*)d_ws;
    ushort* A_cat  = (ushort*)ws;                                   // 50,331,648 B
    ushort* W_perm = (ushort*)(ws + (size_t)M_ROWS * K_TOT * 2);    // 12,582,912 B
    float*  biasc  = (float*)(ws + (size_t)M_ROWS * K_TOT * 2
                                 + (size_t)N_TOT * K_TOT * 2);      // 16 KB

    float* outc = (float*)d_out;
    float* outh = (float*)d_out + (size_t)M_ROWS * N_HID;

    hipLaunchKernelGGL(build_A, dim3(2048), dim3(256), 0, stream, x, h, A_cat);
    hipLaunchKernelGGL(build_W, dim3(1024), dim3(256), 0, stream,
                       Wii, Wif, Wig, Wio, Whi, Whf, Whg, Who, W_perm);
    hipLaunchKernelGGL(build_bias, dim3(16), dim3(256), 0, stream,
                       bii, bif, big, bio, bhi, bhf, bhg, bho, biasc);
    hipLaunchKernelGGL(lstm_gemm, dim3(M_ROWS / BM, N_TOT / BN), dim3(256), 0, stream,
                       A_cat, W_perm, biasc, c, outc, outh);
}

// Round 4
// 280.829 us; speedup vs baseline: 1.2908x; 1.0597x over previous
//
#include <hip/hip_runtime.h>
#include <hip/hip_bf16.h>

#define M_ROWS 16384
#define N_IN   512
#define N_HID  1024
#define K_TOT  1536   // 512 + 1024
#define N_TOT  4096   // 4 gates * 1024

typedef __attribute__((ext_vector_type(4))) float f32x4;
typedef __attribute__((ext_vector_type(8))) short bf16x8;

__device__ __forceinline__ ushort f2bf(float f) {
    union { float f; unsigned u; } un; un.f = f;
    unsigned u = un.u;
    u += 0x7fffu + ((u >> 16) & 1u);   // RNE
    return (ushort)(u >> 16);
}

// ---------------- prep kernels ----------------

__global__ void build_A(const float* __restrict__ x, const float* __restrict__ h,
                        ushort* __restrict__ A) {
    const int total = M_ROWS * K_TOT / 4;
    for (int p = blockIdx.x * blockDim.x + threadIdx.x; p < total;
         p += gridDim.x * blockDim.x) {
        int flat = p * 4;
        int row = flat / K_TOT;
        int col = flat - row * K_TOT;
        const float* src = (col < N_IN)
            ? (x + (size_t)row * N_IN + col)
            : (h + (size_t)row * N_HID + (col - N_IN));
        float4 v = *(const float4*)src;
        ushort4 o;
        o.x = f2bf(v.x); o.y = f2bf(v.y); o.z = f2bf(v.z); o.w = f2bf(v.w);
        *(ushort4*)(A + flat) = o;
    }
}

// W_perm row p: group = p>>7, cc = (p>>6)&1, g = (p>>4)&3, u = p&15
// source row j = group*32 + cc*16 + u of gate g; k<512 -> Wx_g else Wh_g
__global__ void build_W(const float* __restrict__ Wii, const float* __restrict__ Wif,
                        const float* __restrict__ Wig, const float* __restrict__ Wio,
                        const float* __restrict__ Whi, const float* __restrict__ Whf,
                        const float* __restrict__ Whg, const float* __restrict__ Who,
                        ushort* __restrict__ Wp) {
    const int total = N_TOT * K_TOT / 4;
    for (int p = blockIdx.x * blockDim.x + threadIdx.x; p < total;
         p += gridDim.x * blockDim.x) {
        int flat = p * 4;
        int prow = flat / K_TOT;
        int col = flat - prow * K_TOT;
        int grp = prow >> 7;
        int tt = prow & 127;
        int cc = (tt >> 6) & 1;
        int ss = tt & 63;
        int g  = ss >> 4;
        int u  = ss & 15;
        int j  = grp * 32 + cc * 16 + u;
        const float* src;
        if (col < N_IN) {
            const float* Wx = (g == 0) ? Wii : (g == 1) ? Wif : (g == 2) ? Wig : Wio;
            src = Wx + (size_t)j * N_IN + col;
        } else {
            const float* Wh = (g == 0) ? Whi : (g == 1) ? Whf : (g == 2) ? Whg : Who;
            src = Wh + (size_t)j * N_HID + (col - N_IN);
        }
        float4 v = *(const float4*)src;
        ushort4 o;
        o.x = f2bf(v.x); o.y = f2bf(v.y); o.z = f2bf(v.z); o.w = f2bf(v.w);
        *(ushort4*)(Wp + flat) = o;
    }
}

__global__ void build_bias(const float* __restrict__ bii, const float* __restrict__ bif,
                           const float* __restrict__ big, const float* __restrict__ bio,
                           const float* __restrict__ bhi, const float* __restrict__ bhf,
                           const float* __restrict__ bhg, const float* __restrict__ bho,
                           float* __restrict__ bias) {
    int n = blockIdx.x * blockDim.x + threadIdx.x;
    if (n >= N_TOT) return;
    int g = n >> 10, j = n & 1023;
    const float* bx = (g == 0) ? bii : (g == 1) ? bif : (g == 2) ? big : bio;
    const float* bh = (g == 0) ? bhi : (g == 1) ? bhf : (g == 2) ? bhg : bho;
    bias[n] = bx[j] + bh[j];
}

// ---------------- fused 8-phase GEMM + LSTM epilogue ----------------
// 256x256 tile, BK=64, 2 K-tiles/iter, 8 waves (2M x 4N), per-wave 128x64.
// LDS: sA/sB [dbuf][half][128][64], XOR-8 chunk swizzle (proven 0-conflict).
// Phases P1-4 compute even tile (dbuf0), P5-8 odd tile (dbuf1); quadrants
// (mh,nh) = (0,0),(0,1),(1,1),(1,0). Stage ledger (consumed -> staged):
//   d0.B @P2 -> P3,P4 | d0.A @P3 -> P5,P6 | d1.B @P6 -> P7,P8 | d1.A @P7 -> P1,P2(next)
// vmcnt(4) before P4/P8 end-barriers gates the next K-tile's data.

__device__ __forceinline__ float sigmoid_f(float z) {
    return 1.f / (1.f + __expf(-z));
}
__device__ __forceinline__ float tanh_f(float z) {
    z = fminf(fmaxf(z, -15.f), 15.f);
    float e = __expf(2.f * z);
    return (e - 1.f) / (e + 1.f);
}

__global__ __launch_bounds__(512, 1) void lstm_gemm(
        const ushort* __restrict__ A, const ushort* __restrict__ W,
        const float* __restrict__ bias, const float* __restrict__ cin,
        float* __restrict__ outc, float* __restrict__ outh) {
    __shared__ ushort sA[2][2][128 * 64];   // 64 KB
    __shared__ ushort sB[2][2][128 * 64];   // 64 KB

    const int tid  = threadIdx.x;
    const int wid  = tid >> 6;
    const int lane = tid & 63;
    const int wr  = wid >> 2;    // 0..1  (M half)
    const int wcn = wid & 3;     // 0..3  (N quarter)
    const int m0 = blockIdx.x * 256;
    const int n0 = blockIdx.y * 256;

    f32x4 acc[8][4] = {};

    // staging: call i covers rows i*64 + (tid>>3), swizzled source chunk
    const int srow = tid >> 3;                       // 0..63
    const int fch  = (tid & 7) ^ (srow & 7);         // involution
    const ushort* gA = A + (size_t)(m0 + srow) * K_TOT + fch * 8;
    const ushort* gB = W + (size_t)(n0 + srow) * K_TOT + fch * 8;

#define GLDS(gptr, lptr) __builtin_amdgcn_global_load_lds(                     \
        (const __attribute__((address_space(1))) void*)(gptr),                 \
        (__attribute__((address_space(3))) void*)(lptr), 16, 0, 0)

#define STAGE_A(db, hh, kt) do {                                               \
    GLDS(gA + (size_t)((hh) * 128 + 0) * K_TOT + (size_t)(kt) * 64,            \
         &sA[db][hh][0 * 4096 + tid * 8]);                                     \
    GLDS(gA + (size_t)((hh) * 128 + 64) * K_TOT + (size_t)(kt) * 64,           \
         &sA[db][hh][1 * 4096 + tid * 8]);                                     \
} while (0)

#define STAGE_B(db, hh, kt) do {                                               \
    GLDS(gB + (size_t)((hh) * 128 + 0) * K_TOT + (size_t)(kt) * 64,            \
         &sB[db][hh][0 * 4096 + tid * 8]);                                     \
    GLDS(gB + (size_t)((hh) * 128 + 64) * K_TOT + (size_t)(kt) * 64,           \
         &sB[db][hh][1 * 4096 + tid * 8]);                                     \
} while (0)

    const int lrow = lane & 15;
    const int cb0  = lane >> 4;      // 0..3
    const int csw  = lrow & 7;

#define LOADA(db, mh) do {                                                     \
    _Pragma("unroll")                                                          \
    for (int m = 0; m < 4; ++m)                                                \
        _Pragma("unroll")                                                      \
        for (int kk = 0; kk < 2; ++kk)                                         \
            af[m][kk] = *(const bf16x8*)&sA[db][wr]                            \
                [((mh) * 64 + m * 16 + lrow) * 64 + ((kk * 4 + cb0) ^ csw) * 8]; \
} while (0)

#define LOADB(db, nh, dst) do {                                                \
    _Pragma("unroll")                                                          \
    for (int n = 0; n < 2; ++n)                                                \
        _Pragma("unroll")                                                      \
        for (int kk = 0; kk < 2; ++kk)                                         \
            dst[n][kk] = *(const bf16x8*)&sB[db][wcn >> 1]                     \
                [((wcn & 1) * 64 + ((nh) * 2 + n) * 16 + lrow) * 64            \
                 + ((kk * 4 + cb0) ^ csw) * 8];                                \
} while (0)

#define MFMA_Q(mh, nh, bsrc) do {                                              \
    __builtin_amdgcn_s_setprio(1);                                             \
    _Pragma("unroll")                                                          \
    for (int m = 0; m < 4; ++m)                                                \
        _Pragma("unroll")                                                      \
        for (int n = 0; n < 2; ++n) {                                          \
            acc[(mh) * 4 + m][(nh) * 2 + n] =                                  \
                __builtin_amdgcn_mfma_f32_16x16x32_bf16(                       \
                    af[m][0], bsrc[n][0], acc[(mh) * 4 + m][(nh) * 2 + n], 0, 0, 0); \
            acc[(mh) * 4 + m][(nh) * 2 + n] =                                  \
                __builtin_amdgcn_mfma_f32_16x16x32_bf16(                       \
                    af[m][1], bsrc[n][1], acc[(mh) * 4 + m][(nh) * 2 + n], 0, 0, 0); \
        }                                                                      \
    __builtin_amdgcn_s_setprio(0);                                             \
} while (0)

#define BARX() do {                                                            \
    __builtin_amdgcn_sched_barrier(0);                                         \
    __builtin_amdgcn_s_barrier();                                              \
    __builtin_amdgcn_sched_barrier(0);                                         \
} while (0)

#define VMC(n) asm volatile("s_waitcnt vmcnt(" #n ")" ::: "memory")

    bf16x8 af[4][2], bf0[2][2], bf1[2][2];

    // prologue: t0 complete (dbuf0) + t1.B (dbuf1); wait t0 landed
    STAGE_A(0, 0, 0); STAGE_A(0, 1, 0);
    STAGE_B(0, 0, 0); STAGE_B(0, 1, 0);
    STAGE_B(1, 0, 1); STAGE_B(1, 1, 1);
    __builtin_amdgcn_sched_barrier(0);
    VMC(4);
    __builtin_amdgcn_s_barrier();
    __builtin_amdgcn_sched_barrier(0);

    for (int it = 0; it < 11; ++it) {
        const int ka = 2 * it;
        // P1: read d0.A(mh0)+d0.B(nh0); stage d1.A h0 (tile ka+1)
        LOADA(0, 0); LOADB(0, 0, bf0);
        STAGE_A(1, 0, ka + 1);
        BARX(); MFMA_Q(0, 0, bf0); BARX();
        // P2: read d0.B(nh1); stage d1.A h1
        LOADB(0, 1, bf1);
        STAGE_A(1, 1, ka + 1);
        BARX(); MFMA_Q(0, 1, bf1); BARX();
        // P3: read d0.A(mh1); stage d0.B h0 (tile ka+2)
        LOADA(0, 1);
        STAGE_B(0, 0, ka + 2);
        BARX(); MFMA_Q(1, 1, bf1); BARX();
        // P4: stage d0.B h1; vmcnt(4) gates tile ka+1
        STAGE_B(0, 1, ka + 2);
        BARX(); MFMA_Q(1, 0, bf0);
        VMC(4); BARX();
        // P5: read d1.A(mh0)+d1.B(nh0); stage d0.A h0 (tile ka+2)
        LOADA(1, 0); LOADB(1, 0, bf0);
        STAGE_A(0, 0, ka + 2);
        BARX(); MFMA_Q(0, 0, bf0); BARX();
        // P6: read d1.B(nh1); stage d0.A h1
        LOADB(1, 1, bf1);
        STAGE_A(0, 1, ka + 2);
        BARX(); MFMA_Q(0, 1, bf1); BARX();
        // P7: read d1.A(mh1); stage d1.B h0 (tile ka+3)
        LOADA(1, 1);
        STAGE_B(1, 0, ka + 3);
        BARX(); MFMA_Q(1, 1, bf1); BARX();
        // P8: stage d1.B h1; vmcnt(4) gates tile ka+2
        STAGE_B(1, 1, ka + 3);
        BARX(); MFMA_Q(1, 0, bf0);
        VMC(4); BARX();
    }

    // peeled last iteration: tiles 22 (dbuf0), 23 (dbuf1); stage only t23.A
    LOADA(0, 0); LOADB(0, 0, bf0);
    STAGE_A(1, 0, 23);
    BARX(); MFMA_Q(0, 0, bf0); BARX();
    LOADB(0, 1, bf1);
    STAGE_A(1, 1, 23);
    BARX(); MFMA_Q(0, 1, bf1); BARX();
    LOADA(0, 1);
    BARX(); MFMA_Q(1, 1, bf1); BARX();
    BARX(); MFMA_Q(1, 0, bf0);
    VMC(0); BARX();
    LOADA(1, 0); LOADB(1, 0, bf0);
    BARX(); MFMA_Q(0, 0, bf0); BARX();
    LOADB(1, 1, bf1);
    BARX(); MFMA_Q(0, 1, bf1); BARX();
    LOADA(1, 1);
    BARX(); MFMA_Q(1, 1, bf1); BARX();
    BARX(); MFMA_Q(1, 0, bf0);

    // epilogue: lane owns unit; gates = acc[mi][0..3]
    const int unit = (2 * blockIdx.y + (wcn >> 1)) * 32 + (wcn & 1) * 16 + lrow;
    const float b0 = bias[unit];
    const float b1 = bias[1024 + unit];
    const float b2 = bias[2048 + unit];
    const float b3 = bias[3072 + unit];
    const int r0 = m0 + wr * 128 + (lane >> 4) * 4;
#pragma unroll
    for (int mi = 0; mi < 8; ++mi) {
#pragma unroll
        for (int q = 0; q < 4; ++q) {
            const int row = r0 + mi * 16 + q;
            const size_t off = (size_t)row * N_HID + unit;
            float zi = acc[mi][0][q] + b0;
            float zf = acc[mi][1][q] + b1;
            float zg = acc[mi][2][q] + b2;
            float zo = acc[mi][3][q] + b3;
            float it_ = sigmoid_f(zi);
            float ft = sigmoid_f(zf);
            float gt = tanh_f(zg);
            float ot = sigmoid_f(zo);
            float ct = ft * cin[off] + it_ * gt;
            float ht = ot * tanh_f(ct);
            outc[off] = ct;
            outh[off] = ht;
        }
    }
#undef GLDS
#undef STAGE_A
#undef STAGE_B
#undef LOADA
#undef LOADB
#undef MFMA_Q
#undef BARX
#undef VMC
}

// ---------------- launch ----------------

extern "C" void kernel_launch(void* const* d_in, const int* in_sizes, int n_in,
                              void* d_out, int out_size, void* d_ws, size_t ws_size,
                              hipStream_t stream) {
    const float* x = (const float*)d_in[0];
    const float* c = (const float*)d_in[1];
    const float* h = (const float*)d_in[2];
    const float* Wii = (const float*)d_in[3];  const float* bii = (const float*)d_in[4];
    const float* Wif = (const float*)d_in[5];  const float* bif = (const float*)d_in[6];
    const float* Wig = (const float*)d_in[7];  const float* big = (const float*)d_in[8];
    const float* Wio = (const float*)d_in[9];  const float* bio = (const float*)d_in[10];
    const float* Whi = (const float*)d_in[11]; const float* bhi = (const float*)d_in[12];
    const float* Whf = (const float*)d_in[13]; const float* bhf = (const float*)d_in[14];
    const float* Whg = (const float*)d_in[15]; const float* bhg = (const float*)d_in[16];
    const float* Who = (const float*)d_in[17]; const float* bho = (const float*)d_in[18];

    char* ws = (char*)d_ws;
    ushort* A_cat  = (ushort*)ws;                                   // 50,331,648 B
    ushort* W_perm = (ushort*)(ws + (size_t)M_ROWS * K_TOT * 2);    // 12,582,912 B
    float*  biasc  = (float*)(ws + (size_t)M_ROWS * K_TOT * 2
                                 + (size_t)N_TOT * K_TOT * 2);      // 16 KB

    float* outc = (float*)d_out;
    float* outh = (float*)d_out + (size_t)M_ROWS * N_HID;

    hipLaunchKernelGGL(build_A, dim3(2048), dim3(256), 0, stream, x, h, A_cat);
    hipLaunchKernelGGL(build_W, dim3(1024), dim3(256), 0, stream,
                       Wii, Wif, Wig, Wio, Whi, Whf, Whg, Who, W_perm);
    hipLaunchKernelGGL(build_bias, dim3(16), dim3(256), 0, stream,
                       bii, bif, big, bio, bhi, bhf, bhg, bho, biasc);
    hipLaunchKernelGGL(lstm_gemm, dim3(M_ROWS / 256, N_TOT / 256), dim3(512), 0, stream,
                       A_cat, W_perm, biasc, c, outc, outh);
}

// Round 5
// 279.887 us; speedup vs baseline: 1.2951x; 1.0034x over previous
//
#include <hip/hip_runtime.h>
#include <hip/hip_bf16.h>

#define M_ROWS 16384
#define N_IN   512
#define N_HID  1024
#define K_TOT  1536   // 512 + 1024
#define N_TOT  4096   // 4 gates * 1024

typedef __attribute__((ext_vector_type(4))) float f32x4;
typedef __attribute__((ext_vector_type(8))) short bf16x8;

__device__ __forceinline__ ushort f2bf(float f) {
    union { float f; unsigned u; } un; un.f = f;
    unsigned u = un.u;
    u += 0x7fffu + ((u >> 16) & 1u);   // RNE
    return (ushort)(u >> 16);
}

// ---------------- prep kernels ----------------

__global__ void build_A(const float* __restrict__ x, const float* __restrict__ h,
                        ushort* __restrict__ A) {
    const int total = M_ROWS * K_TOT / 4;
    for (int p = blockIdx.x * blockDim.x + threadIdx.x; p < total;
         p += gridDim.x * blockDim.x) {
        int flat = p * 4;
        int row = flat / K_TOT;
        int col = flat - row * K_TOT;
        const float* src = (col < N_IN)
            ? (x + (size_t)row * N_IN + col)
            : (h + (size_t)row * N_HID + (col - N_IN));
        float4 v = *(const float4*)src;
        ushort4 o;
        o.x = f2bf(v.x); o.y = f2bf(v.y); o.z = f2bf(v.z); o.w = f2bf(v.w);
        *(ushort4*)(A + flat) = o;
    }
}

// W_perm row p: group = p>>7, cc = (p>>6)&1, g = (p>>4)&3, u = p&15
// source row j = group*32 + cc*16 + u of gate g; k<512 -> Wx_g else Wh_g
__global__ void build_W(const float* __restrict__ Wii, const float* __restrict__ Wif,
                        const float* __restrict__ Wig, const float* __restrict__ Wio,
                        const float* __restrict__ Whi, const float* __restrict__ Whf,
                        const float* __restrict__ Whg, const float* __restrict__ Who,
                        ushort* __restrict__ Wp) {
    const int total = N_TOT * K_TOT / 4;
    for (int p = blockIdx.x * blockDim.x + threadIdx.x; p < total;
         p += gridDim.x * blockDim.x) {
        int flat = p * 4;
        int prow = flat / K_TOT;
        int col = flat - prow * K_TOT;
        int grp = prow >> 7;
        int tt = prow & 127;
        int cc = (tt >> 6) & 1;
        int ss = tt & 63;
        int g  = ss >> 4;
        int u  = ss & 15;
        int j  = grp * 32 + cc * 16 + u;
        const float* src;
        if (col < N_IN) {
            const float* Wx = (g == 0) ? Wii : (g == 1) ? Wif : (g == 2) ? Wig : Wio;
            src = Wx + (size_t)j * N_IN + col;
        } else {
            const float* Wh = (g == 0) ? Whi : (g == 1) ? Whf : (g == 2) ? Whg : Who;
            src = Wh + (size_t)j * N_HID + (col - N_IN);
        }
        float4 v = *(const float4*)src;
        ushort4 o;
        o.x = f2bf(v.x); o.y = f2bf(v.y); o.z = f2bf(v.z); o.w = f2bf(v.w);
        *(ushort4*)(Wp + flat) = o;
    }
}

__global__ void build_bias(const float* __restrict__ bii, const float* __restrict__ bif,
                           const float* __restrict__ big, const float* __restrict__ bio,
                           const float* __restrict__ bhi, const float* __restrict__ bhf,
                           const float* __restrict__ bhg, const float* __restrict__ bho,
                           float* __restrict__ bias) {
    int n = blockIdx.x * blockDim.x + threadIdx.x;
    if (n >= N_TOT) return;
    int g = n >> 10, j = n & 1023;
    const float* bx = (g == 0) ? bii : (g == 1) ? bif : (g == 2) ? big : bio;
    const float* bh = (g == 0) ? bhi : (g == 1) ? bhf : (g == 2) ? bhg : bho;
    bias[n] = bx[j] + bh[j];
}

// ---------------- fused 8-phase GEMM + LSTM epilogue ----------------
// Identical to round 4 EXCEPT: all sched_barrier(0) pins removed (m141:
// order-pinning defeats compiler scheduling, 1.7x penalty). Bare s_barrier
// is a side-effecting convergent intrinsic -> compiler won't move memory ops
// across it; VMC keeps "memory" clobber so the vmcnt ledger stays exact.
// Ledger (consumed -> staged):
//   d0.B @P2 -> P3,P4 | d0.A @P3 -> P5,P6 | d1.B @P6 -> P7,P8 | d1.A @P7 -> P1,P2(next)
// vmcnt(4) before P4/P8 end-barriers gates the next K-tile's data.

__device__ __forceinline__ float sigmoid_f(float z) {
    return 1.f / (1.f + __expf(-z));
}
__device__ __forceinline__ float tanh_f(float z) {
    z = fminf(fmaxf(z, -15.f), 15.f);
    float e = __expf(2.f * z);
    return (e - 1.f) / (e + 1.f);
}

__global__ __launch_bounds__(512, 1) void lstm_gemm(
        const ushort* __restrict__ A, const ushort* __restrict__ W,
        const float* __restrict__ bias, const float* __restrict__ cin,
        float* __restrict__ outc, float* __restrict__ outh) {
    __shared__ ushort sA[2][2][128 * 64];   // 64 KB
    __shared__ ushort sB[2][2][128 * 64];   // 64 KB

    const int tid  = threadIdx.x;
    const int wid  = tid >> 6;
    const int lane = tid & 63;
    const int wr  = wid >> 2;    // 0..1  (M half)
    const int wcn = wid & 3;     // 0..3  (N quarter)
    const int m0 = blockIdx.x * 256;
    const int n0 = blockIdx.y * 256;

    f32x4 acc[8][4] = {};

    // staging: call i covers rows i*64 + (tid>>3), swizzled source chunk
    const int srow = tid >> 3;                       // 0..63
    const int fch  = (tid & 7) ^ (srow & 7);         // involution
    const ushort* gA = A + (size_t)(m0 + srow) * K_TOT + fch * 8;
    const ushort* gB = W + (size_t)(n0 + srow) * K_TOT + fch * 8;

#define GLDS(gptr, lptr) __builtin_amdgcn_global_load_lds(                     \
        (const __attribute__((address_space(1))) void*)(gptr),                 \
        (__attribute__((address_space(3))) void*)(lptr), 16, 0, 0)

#define STAGE_A(db, hh, kt) do {                                               \
    GLDS(gA + (size_t)((hh) * 128 + 0) * K_TOT + (size_t)(kt) * 64,            \
         &sA[db][hh][0 * 4096 + tid * 8]);                                     \
    GLDS(gA + (size_t)((hh) * 128 + 64) * K_TOT + (size_t)(kt) * 64,           \
         &sA[db][hh][1 * 4096 + tid * 8]);                                     \
} while (0)

#define STAGE_B(db, hh, kt) do {                                               \
    GLDS(gB + (size_t)((hh) * 128 + 0) * K_TOT + (size_t)(kt) * 64,            \
         &sB[db][hh][0 * 4096 + tid * 8]);                                     \
    GLDS(gB + (size_t)((hh) * 128 + 64) * K_TOT + (size_t)(kt) * 64,           \
         &sB[db][hh][1 * 4096 + tid * 8]);                                     \
} while (0)

    const int lrow = lane & 15;
    const int cb0  = lane >> 4;      // 0..3
    const int csw  = lrow & 7;

#define LOADA(db, mh) do {                                                     \
    _Pragma("unroll")                                                          \
    for (int m = 0; m < 4; ++m)                                                \
        _Pragma("unroll")                                                      \
        for (int kk = 0; kk < 2; ++kk)                                         \
            af[m][kk] = *(const bf16x8*)&sA[db][wr]                            \
                [((mh) * 64 + m * 16 + lrow) * 64 + ((kk * 4 + cb0) ^ csw) * 8]; \
} while (0)

#define LOADB(db, nh, dst) do {                                                \
    _Pragma("unroll")                                                          \
    for (int n = 0; n < 2; ++n)                                                \
        _Pragma("unroll")                                                      \
        for (int kk = 0; kk < 2; ++kk)                                         \
            dst[n][kk] = *(const bf16x8*)&sB[db][wcn >> 1]                     \
                [((wcn & 1) * 64 + ((nh) * 2 + n) * 16 + lrow) * 64            \
                 + ((kk * 4 + cb0) ^ csw) * 8];                                \
} while (0)

#define MFMA_Q(mh, nh, bsrc) do {                                              \
    __builtin_amdgcn_s_setprio(1);                                             \
    _Pragma("unroll")                                                          \
    for (int m = 0; m < 4; ++m)                                                \
        _Pragma("unroll")                                                      \
        for (int n = 0; n < 2; ++n) {                                          \
            acc[(mh) * 4 + m][(nh) * 2 + n] =                                  \
                __builtin_amdgcn_mfma_f32_16x16x32_bf16(                       \
                    af[m][0], bsrc[n][0], acc[(mh) * 4 + m][(nh) * 2 + n], 0, 0, 0); \
            acc[(mh) * 4 + m][(nh) * 2 + n] =                                  \
                __builtin_amdgcn_mfma_f32_16x16x32_bf16(                       \
                    af[m][1], bsrc[n][1], acc[(mh) * 4 + m][(nh) * 2 + n], 0, 0, 0); \
        }                                                                      \
    __builtin_amdgcn_s_setprio(0);                                             \
} while (0)

#define BARX() __builtin_amdgcn_s_barrier()

#define VMC(n) asm volatile("s_waitcnt vmcnt(" #n ")" ::: "memory")

    bf16x8 af[4][2], bf0[2][2], bf1[2][2];

    // prologue: t0 complete (dbuf0) + t1.B (dbuf1); wait t0 landed
    STAGE_A(0, 0, 0); STAGE_A(0, 1, 0);
    STAGE_B(0, 0, 0); STAGE_B(0, 1, 0);
    STAGE_B(1, 0, 1); STAGE_B(1, 1, 1);
    VMC(4);
    __builtin_amdgcn_s_barrier();

    for (int it = 0; it < 11; ++it) {
        const int ka = 2 * it;
        // P1: read d0.A(mh0)+d0.B(nh0); stage d1.A h0 (tile ka+1)
        LOADA(0, 0); LOADB(0, 0, bf0);
        STAGE_A(1, 0, ka + 1);
        BARX(); MFMA_Q(0, 0, bf0); BARX();
        // P2: read d0.B(nh1); stage d1.A h1
        LOADB(0, 1, bf1);
        STAGE_A(1, 1, ka + 1);
        BARX(); MFMA_Q(0, 1, bf1); BARX();
        // P3: read d0.A(mh1); stage d0.B h0 (tile ka+2)
        LOADA(0, 1);
        STAGE_B(0, 0, ka + 2);
        BARX(); MFMA_Q(1, 1, bf1); BARX();
        // P4: stage d0.B h1; vmcnt(4) gates tile ka+1
        STAGE_B(0, 1, ka + 2);
        BARX(); MFMA_Q(1, 0, bf0);
        VMC(4); BARX();
        // P5: read d1.A(mh0)+d1.B(nh0); stage d0.A h0 (tile ka+2)
        LOADA(1, 0); LOADB(1, 0, bf0);
        STAGE_A(0, 0, ka + 2);
        BARX(); MFMA_Q(0, 0, bf0); BARX();
        // P6: read d1.B(nh1); stage d0.A h1
        LOADB(1, 1, bf1);
        STAGE_A(0, 1, ka + 2);
        BARX(); MFMA_Q(0, 1, bf1); BARX();
        // P7: read d1.A(mh1); stage d1.B h0 (tile ka+3)
        LOADA(1, 1);
        STAGE_B(1, 0, ka + 3);
        BARX(); MFMA_Q(1, 1, bf1); BARX();
        // P8: stage d1.B h1; vmcnt(4) gates tile ka+2
        STAGE_B(1, 1, ka + 3);
        BARX(); MFMA_Q(1, 0, bf0);
        VMC(4); BARX();
    }

    // peeled last iteration: tiles 22 (dbuf0), 23 (dbuf1); stage only t23.A
    LOADA(0, 0); LOADB(0, 0, bf0);
    STAGE_A(1, 0, 23);
    BARX(); MFMA_Q(0, 0, bf0); BARX();
    LOADB(0, 1, bf1);
    STAGE_A(1, 1, 23);
    BARX(); MFMA_Q(0, 1, bf1); BARX();
    LOADA(0, 1);
    BARX(); MFMA_Q(1, 1, bf1); BARX();
    BARX(); MFMA_Q(1, 0, bf0);
    VMC(0); BARX();
    LOADA(1, 0); LOADB(1, 0, bf0);
    BARX(); MFMA_Q(0, 0, bf0); BARX();
    LOADB(1, 1, bf1);
    BARX(); MFMA_Q(0, 1, bf1); BARX();
    LOADA(1, 1);
    BARX(); MFMA_Q(1, 1, bf1); BARX();
    BARX(); MFMA_Q(1, 0, bf0);

    // epilogue: lane owns unit; gates = acc[mi][0..3]
    const int unit = (2 * blockIdx.y + (wcn >> 1)) * 32 + (wcn & 1) * 16 + lrow;
    const float b0 = bias[unit];
    const float b1 = bias[1024 + unit];
    const float b2 = bias[2048 + unit];
    const float b3 = bias[3072 + unit];
    const int r0 = m0 + wr * 128 + (lane >> 4) * 4;
#pragma unroll
    for (int mi = 0; mi < 8; ++mi) {
#pragma unroll
        for (int q = 0; q < 4; ++q) {
            const int row = r0 + mi * 16 + q;
            const size_t off = (size_t)row * N_HID + unit;
            float zi = acc[mi][0][q] + b0;
            float zf = acc[mi][1][q] + b1;
            float zg = acc[mi][2][q] + b2;
            float zo = acc[mi][3][q] + b3;
            float it_ = sigmoid_f(zi);
            float ft = sigmoid_f(zf);
            float gt = tanh_f(zg);
            float ot = sigmoid_f(zo);
            float ct = ft * cin[off] + it_ * gt;
            float ht = ot * tanh_f(ct);
            outc[off] = ct;
            outh[off] = ht;
        }
    }
#undef GLDS
#undef STAGE_A
#undef STAGE_B
#undef LOADA
#undef LOADB
#undef MFMA_Q
#undef BARX
#undef VMC
}

// ---------------- launch ----------------

extern "C" void kernel_launch(void* const* d_in, const int* in_sizes, int n_in,
                              void* d_out, int out_size, void* d_ws, size_t ws_size,
                              hipStream_t stream) {
    const float* x = (const float*)d_in[0];
    const float* c = (const float*)d_in[1];
    const float* h = (const float*)d_in[2];
    const float* Wii = (const float*)d_in[3];  const float* bii = (const float*)d_in[4];
    const float* Wif = (const float*)d_in[5];  const float* bif = (const float*)d_in[6];
    const float* Wig = (const float*)d_in[7];  const float* big = (const float*)d_in[8];
    const float* Wio = (const float*)d_in[9];  const float* bio = (const float*)d_in[10];
    const float* Whi = (const float*)d_in[11]; const float* bhi = (const float*)d_in[12];
    const float* Whf = (const float*)d_in[13]; const float* bhf = (const float*)d_in[14];
    const float* Whg = (const float*)d_in[15]; const float* bhg = (const float*)d_in[16];
    const float* Who = (const float*)d_in[17]; const float* bho = (const float*)d_in[18];

    char* ws = (char*)d_ws;
    ushort* A_cat  = (ushort*)ws;                                   // 50,331,648 B
    ushort* W_perm = (ushort*)(ws + (size_t)M_ROWS * K_TOT * 2);    // 12,582,912 B
    float*  biasc  = (float*)(ws + (size_t)M_ROWS * K_TOT * 2
                                 + (size_t)N_TOT * K_TOT * 2);      // 16 KB

    float* outc = (float*)d_out;
    float* outh = (float*)d_out + (size_t)M_ROWS * N_HID;

    hipLaunchKernelGGL(build_A, dim3(2048), dim3(256), 0, stream, x, h, A_cat);
    hipLaunchKernelGGL(build_W, dim3(1024), dim3(256), 0, stream,
                       Wii, Wif, Wig, Wio, Whi, Whf, Whg, Who, W_perm);
    hipLaunchKernelGGL(build_bias, dim3(16), dim3(256), 0, stream,
                       bii, bif, big, bio, bhi, bhf, bhg, bho, biasc);
    hipLaunchKernelGGL(lstm_gemm, dim3(M_ROWS / 256, N_TOT / 256), dim3(512), 0, stream,
                       A_cat, W_perm, biasc, c, outc, outh);
}